// Round 7
// baseline (955.590 us; speedup 1.0000x reference)
//
#include <hip/hip_runtime.h>
#include <hip/hip_bf16.h>
#include <stdint.h>

// ---------------------------------------------------------------------------
// GraphAttentionLayer: out = softmax(lrelu(s1_i + s2_j)) @ h,  h = x @ W^T
// Round 10: boundary attack. Content model + R4 coop measurement say ~250us
// of the 492us non-GEMM time is kernel-boundary cost (launch + per-XCD L2
// wb-inv per handoff), not kernel content. 6 kernels -> 4 via ticket-gated
// producer/consumer fusion (first-N-SCHEDULED blocks produce -> release-fence
// -> acquire-spin; deadlock-free by ticket-order induction, all blocks
// co-resident):
//   cvt_all | gemm(+s12, frozen) | rcmp1{rankcount(128)->mega(1)+pass1(512)}
//   | bfp2{boff(64)->pass2(512)}
// GEMM frozen: acc(128 AGPR)+124 VGPR = 252/256 -> any reg-hungry change
// spills; BK=32 can't raise occupancy (acc caps 8 waves/CU).
// ---------------------------------------------------------------------------

typedef float  f32x4  __attribute__((ext_vector_type(4)));
typedef __bf16 bf16x8 __attribute__((ext_vector_type(8)));

#define AS1 __attribute__((address_space(1)))
#define AS3 __attribute__((address_space(3)))

constexpr int NB  = 8192;    // batch rows (i and j)
constexpr int DF  = 4096;    // feature dim
constexpr int CH  = 64;      // sweep chunk length
constexpr int NCH = NB / CH; // 128

constexpr int GK  = DF;      // GEMM K
constexpr int BKK = 64;      // GEMM K-tile
constexpr int NT2 = GK / BKK;

__device__ __forceinline__ uint16_t f2bf_u(float f) {   // RNE fp32 -> bf16
  union { float f; uint32_t u; } x; x.f = f;
  return (uint16_t)((x.u + 0x7FFFu + ((x.u >> 16) & 1u)) >> 16);
}
__device__ __forceinline__ float bfu2f(uint16_t v) {
  union { uint32_t u; float f; } x; x.u = ((uint32_t)v) << 16;
  return x.f;
}

// --------------------------- fp32 -> bf16 convert (x and W in one) ----------
__global__ __launch_bounds__(256) void cvt_all(
    const float* __restrict__ x, uint16_t* __restrict__ xb,
    const float* __restrict__ W, uint16_t* __restrict__ Wb,
    float* __restrict__ z1, float* __restrict__ z2, int* __restrict__ tk) {
  const int idx = blockIdx.x * 256 + threadIdx.x;
  const int stride = gridDim.x * 256;
  const int n4x = (NB * DF) / 4, n4w = (DF * DF) / 4;
  if (idx < NB) { z1[idx] = 0.f; z2[idx] = 0.f; }   // gemm atomic targets
  if (idx < 4) tk[idx] = 0;                          // ticket/done counters
  for (int i = idx; i < n4x; i += stride) {
    float4 v = ((const float4*)x)[i];
    ushort4 o;
    o.x = f2bf_u(v.x); o.y = f2bf_u(v.y); o.z = f2bf_u(v.z); o.w = f2bf_u(v.w);
    ((ushort4*)xb)[i] = o;
  }
  for (int i = idx; i < n4w; i += stride) {
    float4 v = ((const float4*)W)[i];
    ushort4 o;
    o.x = f2bf_u(v.x); o.y = f2bf_u(v.y); o.z = f2bf_u(v.z); o.w = f2bf_u(v.w);
    ((ushort4*)Wb)[i] = o;
  }
}

// --------------------------- NT bf16 GEMM (frozen, R6) ----------------------
#define STAGE_A(tt, half) do {                                                 \
  const uint16_t* g0_ = Ag + (size_t)((half) * 128) * GK + (size_t)(tt) * BKK; \
  uint32_t d_ = ((uint32_t)((tt) & 1)) * 32768u + (uint32_t)(half) * 8192u +   \
                (uint32_t)wave * 512u;                                         \
  __builtin_amdgcn_global_load_lds((const AS1 void*)g0_,                       \
      (AS3 void*)(lds + d_), 16, 0, 0);                                        \
  __builtin_amdgcn_global_load_lds((const AS1 void*)(g0_ + (size_t)64 * GK),   \
      (AS3 void*)(lds + d_ + 4096u), 16, 0, 0);                                \
} while (0)

#define STAGE_B(tt, half) do {                                                 \
  const uint16_t* g0_ = Bg + (size_t)((half) * 128) * GK + (size_t)(tt) * BKK; \
  uint32_t d_ = ((uint32_t)((tt) & 1)) * 32768u + 16384u +                     \
                (uint32_t)(half) * 8192u + (uint32_t)wave * 512u;              \
  __builtin_amdgcn_global_load_lds((const AS1 void*)g0_,                       \
      (AS3 void*)(lds + d_), 16, 0, 0);                                        \
  __builtin_amdgcn_global_load_lds((const AS1 void*)(g0_ + (size_t)64 * GK),   \
      (AS3 void*)(lds + d_ + 4096u), 16, 0, 0);                                \
} while (0)

#define LDA(mh) do {                                                           \
  _Pragma("unroll") for (int mf = 0; mf < 4; ++mf)                             \
    _Pragma("unroll") for (int ks = 0; ks < 2; ++ks)                           \
      aF[mf][ks] = *(const bf16x8*)(lds + bufo +                               \
          (uint32_t)(wm * 128 + (mh) * 64 + mf * 16 + lr) * 64u +              \
          (uint32_t)((ks * 32 + lg * 8) ^ swl));                               \
} while (0)

#define LDB(nh) do {                                                           \
  _Pragma("unroll") for (int nf = 0; nf < 2; ++nf)                             \
    _Pragma("unroll") for (int ks = 0; ks < 2; ++ks)                           \
      bF[nf][ks] = *(const bf16x8*)(lds + bufo + 16384u +                      \
          (uint32_t)(wn * 64 + (nh) * 32 + nf * 16 + lr) * 64u +               \
          (uint32_t)((ks * 32 + lg * 8) ^ swl));                               \
} while (0)

#define MMA(mh, nh) do {                                                       \
  _Pragma("unroll") for (int ks = 0; ks < 2; ++ks)                             \
    _Pragma("unroll") for (int mf = 0; mf < 4; ++mf)                           \
      _Pragma("unroll") for (int nf = 0; nf < 2; ++nf)                         \
        acc[(mh) * 4 + mf][(nh) * 2 + nf] =                                    \
            __builtin_amdgcn_mfma_f32_16x16x32_bf16(aF[mf][ks], bF[nf][ks],    \
                acc[(mh) * 4 + mf][(nh) * 2 + nf], 0, 0, 0);                   \
} while (0)

__global__ __launch_bounds__(512, 2) void gemm_nt_async(
    const uint16_t* __restrict__ A, const uint16_t* __restrict__ B,
    uint16_t* __restrict__ C, const float* __restrict__ a,
    float* __restrict__ s1g, float* __restrict__ s2g) {
  __shared__ uint16_t lds[65536];   // 128 KiB: [buf][A|B][256*64]

  const int tid  = threadIdx.x;
  const int wave = tid >> 6;
  const int lane = tid & 63;
  const int lr   = lane & 15;
  const int lg   = lane >> 4;        // 0..3
  const int wm   = wave >> 2;        // 0..1  (M half)
  const int wn   = wave & 3;         // 0..3  (N quarter)
  const int swl  = (lr & 7) << 3;    // read-side XOR swizzle (elements)

  const int bid = blockIdx.x;
  const int swz = (bid & 7) * 64 + (bid >> 3);
  const int bx  = swz & 15;          // N tile (16)
  const int by  = swz >> 4;          // M tile (32)
  const int rowBase = by * 256;
  const int colBase = bx * 256;

  const int sr  = tid >> 3;                    // 0..63
  const int sch = (tid & 7) ^ (sr & 7);
  const uint16_t* Ag = A + (size_t)(rowBase + sr) * GK + sch * 8;
  const uint16_t* Bg = B + (size_t)(colBase + sr) * GK + sch * 8;

  f32x4 acc[8][4];
#pragma unroll
  for (int mf = 0; mf < 8; ++mf)
#pragma unroll
    for (int nf = 0; nf < 4; ++nf) acc[mf][nf] = (f32x4){0.f, 0.f, 0.f, 0.f};

  STAGE_A(0, 0);
  STAGE_A(0, 1);
  STAGE_B(0, 0);
  STAGE_B(0, 1);
  asm volatile("s_waitcnt vmcnt(0)" ::: "memory");
  __builtin_amdgcn_s_barrier();

  bf16x8 aF[4][2], bF[2][2];

  for (int t = 0; t < NT2; ++t) {
    const uint32_t bufo = ((uint32_t)(t & 1)) * 32768u;

    if (t + 1 < NT2) {
      STAGE_A(t + 1, 0);
      STAGE_A(t + 1, 1);
      STAGE_B(t + 1, 0);
      STAGE_B(t + 1, 1);
    }

    LDA(0); LDB(0);
    MMA(0, 0);
    LDB(1);
    MMA(0, 1);
    LDA(1);
    MMA(1, 1);
    LDB(0);          // re-read B-half0 (cheaper than +16 live VGPRs: 252/256)
    MMA(1, 0);

    if (t + 1 < NT2) {
      asm volatile("s_waitcnt vmcnt(0)" ::: "memory");
      __builtin_amdgcn_s_barrier();
    }
  }

  const int r0 = rowBase + wm * 128 + lg * 4;
  const int c0 = colBase + wn * 64 + lr;
#pragma unroll
  for (int mf = 0; mf < 8; ++mf)
#pragma unroll
    for (int nf = 0; nf < 4; ++nf)
#pragma unroll
      for (int e = 0; e < 4; ++e)
        C[(size_t)(r0 + mf * 16 + e) * (size_t)DF + (c0 + nf * 16)] =
            f2bf_u(acc[mf][nf][e]);

  // ---- s12: per-wave quarter partials -> LDS -> one atomic per row ----
  float a1v[4], a2v[4];
#pragma unroll
  for (int nf = 0; nf < 4; ++nf) {
    int col = c0 + nf * 16;
    a1v[nf] = a[col];
    a2v[nf] = a[DF + col];
  }
  float* sP = (float*)lds;   // buf0-A region dead (last tile odd -> reads buf1)
#pragma unroll
  for (int mf = 0; mf < 8; ++mf) {
#pragma unroll
    for (int e = 0; e < 4; ++e) {
      float p1 = 0.f, p2 = 0.f;
#pragma unroll
      for (int nf = 0; nf < 4; ++nf) {
        float hv = acc[mf][nf][e];
        p1 += hv * a1v[nf];
        p2 += hv * a2v[nf];
      }
      p1 += __shfl_xor(p1, 1, 64); p1 += __shfl_xor(p1, 2, 64);
      p1 += __shfl_xor(p1, 4, 64); p1 += __shfl_xor(p1, 8, 64);
      p2 += __shfl_xor(p2, 1, 64); p2 += __shfl_xor(p2, 2, 64);
      p2 += __shfl_xor(p2, 4, 64); p2 += __shfl_xor(p2, 8, 64);
      if (lr == 0) {
        int rl = wm * 128 + lg * 4 + mf * 16 + e;   // 0..255
        sP[wn * 256 + rl]        = p1;
        sP[1024 + wn * 256 + rl] = p2;
      }
    }
  }
  __syncthreads();
  if (tid < 256) {
    float v1 = sP[tid] + sP[256 + tid] + sP[512 + tid] + sP[768 + tid];
    float v2 = sP[1024 + tid] + sP[1280 + tid] + sP[1536 + tid] + sP[1792 + tid];
    atomicAdd(&s1g[rowBase + tid], v1);
    atomicAdd(&s2g[rowBase + tid], v2);
  }
}

// --------------------------- ticket-gated sync helpers ----------------------
__device__ __forceinline__ int take_ticket(int* tk, int* lds_slot) {
  if (threadIdx.x == 0)
    *lds_slot = __hip_atomic_fetch_add(tk, 1, __ATOMIC_RELAXED,
                                       __HIP_MEMORY_SCOPE_AGENT);
  __syncthreads();
  return *lds_slot;
}
__device__ __forceinline__ void release_done(int* done) {
  __syncthreads();
  __threadfence();
  if (threadIdx.x == 0)
    __hip_atomic_fetch_add(done, 1, __ATOMIC_RELEASE, __HIP_MEMORY_SCOPE_AGENT);
}
__device__ __forceinline__ void acquire_spin(int* done, int target) {
  if (threadIdx.x == 0) {
    while (__hip_atomic_load(done, __ATOMIC_ACQUIRE,
                             __HIP_MEMORY_SCOPE_AGENT) < target)
      __builtin_amdgcn_s_sleep(8);
  }
  __syncthreads();
  __threadfence();
}

// --------------------------- rcmp1: rankcount -> mega + pass1 ---------------
// 513 blocks. Tickets (arrival order, deadlock-free):
//   0..127 : rankcount block T, release; then pass1 role fb=T
//   128    : mega scalar block (scan+finalize+bucketscan+scatter)
//   129..  : pass1 role fb=T-1 (128..511)
union RcSmem {
  float ld[NB];                                                               // rankcount
  struct { float pb[256]; float pc[256]; int histL[NB + 1]; int ps[256]; } mg; // mega
  struct { int pj[CH]; float wb[CH]; float wc[CH]; } pp;                       // pass1
};

__global__ __launch_bounds__(256) void rcmp1_kernel(
    const uint16_t* __restrict__ h,
    const float* __restrict__ s1, const float* __restrict__ s2,
    int* __restrict__ pi, float* __restrict__ s2sorted, int* __restrict__ ci,
    float* __restrict__ wbg, float* __restrict__ wcg,
    float* __restrict__ Sb, float* __restrict__ Sc,
    float* __restrict__ f1, float* __restrict__ f2,
    int* __restrict__ istart, int* __restrict__ ilist,
    float* __restrict__ Bct, float* __restrict__ Cct,
    int* __restrict__ tk) {
  __shared__ RcSmem smu;
  __shared__ int tslot;
  const int t = threadIdx.x;
  const int T = take_ticket(&tk[0], &tslot);

  if (T < 128) {
    // ---- rankcount (block T): 4-part j-scan with +p bank stagger ----
    for (int idx = t; idx < NB; idx += 256) smu.ld[idx] = s2[idx];
    __syncthreads();
    const int i = T * 64 + (t >> 2);
    const int p = t & 3;
    const float v   = smu.ld[i];
    const float thr = -s1[i];
    int cr = 0, cc = 0;
    const int q0 = p * (NB / 16);
    for (int it = 0; it < NB / 16; it++) {
      int qq = q0 + ((it + p) & (NB / 16 - 1));
      float4 u = ((const float4*)smu.ld)[qq];
      int jj = qq * 4;
      cr += (u.x > v) || (u.x == v && (jj + 0) < i);
      cr += (u.y > v) || (u.y == v && (jj + 1) < i);
      cr += (u.z > v) || (u.z == v && (jj + 2) < i);
      cr += (u.w > v) || (u.w == v && (jj + 3) < i);
      cc += (u.x > thr) + (u.y > thr) + (u.z > thr) + (u.w > thr);
    }
    cr += __shfl_xor(cr, 1, 64); cr += __shfl_xor(cr, 2, 64);
    cc += __shfl_xor(cc, 1, 64); cc += __shfl_xor(cc, 2, 64);
    if (p == 0) {
      pi[cr] = i;
      s2sorted[cr] = v;
      ci[i] = cc;
      wbg[cr] = __expf(0.2f * v);
      wcg[cr] = __expf(v);
    }
    release_done(&tk[1]);
  }

  acquire_spin(&tk[1], 128);   // pi/wbg/wcg/ci visible device-wide

  if (T == 128) {
    // ---- mega: scan + finalize + bucket scan + scatter ----
    for (int g = t; g <= NB; g += 256) smu.mg.histL[g] = 0;
    float sb = 0.f, sc = 0.f;
    for (int c = t * 32; c < t * 32 + 32; c++) { sb += wbg[c]; sc += wcg[c]; }
    smu.mg.pb[t] = sb; smu.mg.pc[t] = sc;
    __syncthreads();
    if (t == 0) {
      float rb = 0.f, rc = 0.f;
      for (int q = 0; q < 256; q++) {
        float tb = smu.mg.pb[q], tc = smu.mg.pc[q];
        smu.mg.pb[q] = rb; smu.mg.pc[q] = rc;
        rb += tb; rc += tc;
      }
      Sb[0] = 0.f; Sc[0] = 0.f;
      Sb[NB] = rb; Sc[NB] = rc;
    }
    __syncthreads();
    {
      float rb = smu.mg.pb[t], rc = smu.mg.pc[t];
      for (int c = t * 32; c < t * 32 + 32; c++) {
        rb += wbg[c]; rc += wcg[c];
        if (c + 1 < NB) { Sb[c + 1] = rb; Sc[c + 1] = rc; }
      }
    }
    __syncthreads();
    const float SbT = Sb[NB];
    for (int qq = 0; qq < NB / 256; qq++) {
      int i = qq * 256 + t;
      float s1i = s1[i];
      int c = ci[i];
      float q1 = __expf(0.2f * s1i), q2 = __expf(s1i);
      float l = q1 * (SbT - Sb[c]) + q2 * Sc[c];
      f1[i] = q1 / l;
      f2[i] = q2 / l;
      atomicAdd(&smu.mg.histL[c], 1);
    }
    __syncthreads();
    {
      const int lo = t * 33;
      const int hi = min(lo + 33, NB + 1);
      int s = 0;
      for (int b = lo; b < hi; b++) s += smu.mg.histL[b];
      smu.mg.ps[t] = s;
      __syncthreads();
      if (t == 0) {
        int r = 0;
        for (int q = 0; q < 256; q++) {
          int v = smu.mg.ps[q]; smu.mg.ps[q] = r; r += v;
        }
      }
      __syncthreads();
      int r = smu.mg.ps[t];
      for (int b = lo; b < hi; b++) {
        istart[b] = r;
        int hv = smu.mg.histL[b];
        smu.mg.histL[b] = r;          // cursor
        r += hv;
      }
      if (t == 255) istart[NB + 1] = r;
    }
    __syncthreads();
    for (int qq = 0; qq < NB / 256; qq++) {
      int i = qq * 256 + t;
      int pos = atomicAdd(&smu.mg.histL[ci[i]], 1);
      ilist[pos] = i;
    }
    return;
  }

  // ---- pass1 chunk totals: fb in 0..511 ----
  const int fb = (T < 128) ? T : (T - 1);
  const int cb = fb & 3;
  const int k  = fb >> 2;
  __syncthreads();   // smu reuse (rankcount used ld)
  if (t < CH) {
    int g = k * CH + t;
    smu.pp.pj[t] = pi[g]; smu.pp.wb[t] = wbg[g]; smu.pp.wc[t] = wcg[g];
  }
  __syncthreads();
  const int n0 = cb * 1024 + t * 4;
  float b0 = 0.f, b1 = 0.f, b2 = 0.f, b3 = 0.f;
  float c0 = 0.f, c1 = 0.f, c2 = 0.f, c3 = 0.f;
#pragma unroll 8
  for (int c = 0; c < CH; c++) {
    uint2 hv = *(const uint2*)(h + (size_t)smu.pp.pj[c] * DF + n0);
    float h0 = bfu2f((uint16_t)hv.x), h1 = bfu2f((uint16_t)(hv.x >> 16));
    float h2 = bfu2f((uint16_t)hv.y), h3 = bfu2f((uint16_t)(hv.y >> 16));
    float vb = smu.pp.wb[c], vc = smu.pp.wc[c];
    b0 += vb * h0; b1 += vb * h1; b2 += vb * h2; b3 += vb * h3;
    c0 += vc * h0; c1 += vc * h1; c2 += vc * h2; c3 += vc * h3;
  }
  *(float4*)(Bct + (size_t)k * DF + n0) = make_float4(b0, b1, b2, b3);
  *(float4*)(Cct + (size_t)k * DF + n0) = make_float4(c0, c1, c2, c3);
}

// --------------------------- bfp2: boff -> pass2 ----------------------------
// 512 blocks. Tickets 0..63 do boff strip T first (release), everyone
// acquire-spins on done==64, then all run pass2 role (cb=T&3, k=T>>2).
union BfSmem {
  struct { float sB[4][64]; float sC[4][64]; } bo;
  struct { int pj[CH]; float wb[CH]; float wc[CH]; int se[CH + 2]; } pp;
};

__global__ __launch_bounds__(256) void bfp2_kernel(
    const uint16_t* __restrict__ h, const int* __restrict__ pi,
    const float* __restrict__ wbg, const float* __restrict__ wcg,
    const float* __restrict__ Bct, const float* __restrict__ Cct,
    float* __restrict__ Boff, float* __restrict__ Coff,
    const int* __restrict__ istart, const int* __restrict__ ilist,
    const float* __restrict__ f1, const float* __restrict__ f2,
    float* __restrict__ out, int* __restrict__ tk) {
  __shared__ BfSmem smu;
  __shared__ int tslot;
  const int t = threadIdx.x;
  const int T = take_ticket(&tk[2], &tslot);

  if (T < 64) {
    // ---- boff strip T: per-column chunk-offset scan, cols [T*64, T*64+64) ----
    const int cl  = t & 63;
    const int seg = t >> 6;
    const int col = T * 64 + cl;
    float sb = 0.f, sc = 0.f;
#pragma unroll 8
    for (int u = 0; u < NCH / 4; u++) {
      int kk = seg * (NCH / 4) + u;
      sb += Bct[(size_t)kk * DF + col];
      sc += Cct[(size_t)kk * DF + col];
    }
    smu.bo.sB[seg][cl] = sb; smu.bo.sC[seg][cl] = sc;
    __syncthreads();
    float rb = 0.f, rc = 0.f;
#pragma unroll
    for (int s = 0; s < 3; s++)
      if (s < seg) { rb += smu.bo.sB[s][cl]; rc += smu.bo.sC[s][cl]; }
#pragma unroll 4
    for (int u = 0; u < NCH / 4; u++) {
      int kk = seg * (NCH / 4) + u;
      Boff[(size_t)kk * DF + col] = rb;
      Coff[(size_t)kk * DF + col] = rc;
      rb += Bct[(size_t)kk * DF + col];
      rc += Cct[(size_t)kk * DF + col];
    }
    if (seg == 3) {
      Boff[(size_t)NCH * DF + col] = rb;      // = A_n
      Coff[(size_t)NCH * DF + col] = rc;
    }
    release_done(&tk[3]);
  }

  acquire_spin(&tk[3], 64);   // Boff/Coff visible device-wide

  // ---- pass2: sweep + direct emission ----
  const int cb = T & 3;
  const int k  = T >> 2;
  __syncthreads();   // smu reuse
  if (t < CH) {
    int g = k * CH + t;
    smu.pp.pj[t] = pi[g]; smu.pp.wb[t] = wbg[g]; smu.pp.wc[t] = wcg[g];
  }
  if (t < CH + 2) smu.pp.se[t] = istart[k * CH + t];
  __syncthreads();
  const int n0 = cb * 1024 + t * 4;
  const float4 An = *(const float4*)(Boff + (size_t)NCH * DF + n0);
  const float4 Bo = *(const float4*)(Boff + (size_t)k * DF + n0);
  const float4 Co = *(const float4*)(Coff + (size_t)k * DF + n0);
  float b0 = Bo.x, b1 = Bo.y, b2 = Bo.z, b3 = Bo.w;
  float c0 = Co.x, c1 = Co.y, c2 = Co.z, c3 = Co.w;

  if (k == 0) {   // bucket 0: boundary before any j (c_i == 0)
    for (int idx = smu.pp.se[0]; idx < smu.pp.se[1]; idx++) {
      const int i = ilist[idx];
      const float fa = f1[i];
      *(float4*)(out + (size_t)i * DF + n0) =
          make_float4(fa * An.x, fa * An.y, fa * An.z, fa * An.w);
    }
  }
  for (int c = 0; c < CH; c++) {
    uint2 hv = *(const uint2*)(h + (size_t)smu.pp.pj[c] * DF + n0);
    float h0 = bfu2f((uint16_t)hv.x), h1 = bfu2f((uint16_t)(hv.x >> 16));
    float h2 = bfu2f((uint16_t)hv.y), h3 = bfu2f((uint16_t)(hv.y >> 16));
    float vb = smu.pp.wb[c], vc = smu.pp.wc[c];
    b0 += vb * h0; b1 += vb * h1; b2 += vb * h2; b3 += vb * h3;
    c0 += vc * h0; c1 += vc * h1; c2 += vc * h2; c3 += vc * h3;
    const int e0 = smu.pp.se[c + 1], e1 = smu.pp.se[c + 2];
    for (int idx = e0; idx < e1; idx++) {
      const int i = ilist[idx];
      const float fa = f1[i], fb = f2[i];
      *(float4*)(out + (size_t)i * DF + n0) = make_float4(
          fa * (An.x - b0) + fb * c0, fa * (An.y - b1) + fb * c1,
          fa * (An.z - b2) + fb * c2, fa * (An.w - b3) + fb * c3);
    }
  }
}

// ---------------------------------------------------------------------------
extern "C" void kernel_launch(void* const* d_in, const int* in_sizes, int n_in,
                              void* d_out, int out_size, void* d_ws, size_t ws_size,
                              hipStream_t stream) {
  const float* x = (const float*)d_in[0];   // [8192][4096] fp32
  const float* W = (const float*)d_in[1];   // [4096][4096] fp32
  const float* a = (const float*)d_in[2];   // [8192] fp32
  float* out = (float*)d_out;               // [8192][4096] fp32

  char* ws = (char*)d_ws;
  uint16_t* h = (uint16_t*)ws;                 // 64 MB
  char* sm = ws + 67108864;
  float* s1       = (float*)(sm);
  float* s2       = (float*)(sm + 65536);
  float* s2sorted = (float*)(sm + 131072);
  int*   pi       = (int*)  (sm + 196608);
  int*   ci       = (int*)  (sm + 262144);
  float* Sb       = (float*)(sm + 327680);     // NB+1 floats
  float* Sc       = (float*)(sm + 393216);
  float* wbg      = (float*)(sm + 458752);
  float* wcg      = (float*)(sm + 524288);
  float* f1       = (float*)(sm + 589824);
  float* f2       = (float*)(sm + 655360);
  int*   tk       = (int*)  (sm + 720896);     // ticket/done counters (4 ints)
  int*   istart   = (int*)  (sm + 786432);     // NB+2 ints
  int*   ilist    = (int*)  (sm + 917504);     // NB ints
  float* Bct      = (float*)(sm + 1048576);    // 2 MB
  float* Cct      = (float*)(sm + 3145728);    // 2 MB
  float* Boff     = (float*)(sm + 5242880);    // (NCH+1)*DF*4 ~ 2.02 MB
  float* Coff     = (float*)(sm + 7602176);    // ~2.02 MB (ends sm+9.96MB)
  char* base2 = ws + 67108864 + 10485760;      // staging (dead after gemm)
  uint16_t* xb = (uint16_t*)base2;             // 64 MB
  uint16_t* Wb = (uint16_t*)(base2 + 67108864);// 32 MB  (total ws ~169 MB)

  // 1: cvt x and W (+ zero s1/s2 + ticket counters)
  cvt_all<<<1024, 256, 0, stream>>>(x, xb, W, Wb, s1, s2, tk);

  // 2: GEMM + s12 epilogue (frozen)
  gemm_nt_async<<<(NB / 256) * (DF / 256), 512, 0, stream>>>(
      xb, Wb, h, a, s1, s2);

  // 3: rankcount(128 tickets) -> release -> mega(1) + pass1(512)
  rcmp1_kernel<<<513, 256, 0, stream>>>(
      h, s1, s2, pi, s2sorted, ci, wbg, wcg, Sb, Sc, f1, f2,
      istart, ilist, Bct, Cct, tk);

  // 4: boff(64 tickets) -> release -> pass2(512)
  bfp2_kernel<<<512, 256, 0, stream>>>(
      h, pi, wbg, wcg, Bct, Cct, Boff, Coff, istart, ilist, f1, f2, out, tk);
}